// Round 12
// baseline (112.318 us; speedup 1.0000x reference)
//
#include <hip/hip_runtime.h>
#include <hip/hip_bf16.h>

// ---------------------------------------------------------------------------
// LearnedMeans: 2-NN distances + statistics. R12: long-pipeline A-stationary:
//   dist kernel: wave holds its ENTIRE A panel (16 rows x K=512) in registers
//   (16x bf16x8 = 64 VGPR, statically indexed). Block processes a strip of 4
//   n-chunks serially: K-loop = 32 continuous steps staging ONLY B (8KB/step,
//   2x8KB dbuf, sink-proof global_load_lds, one barrier/step, buf = t&1
//   compile-time). A never re-staged (was re-read from L2 320x across blocks;
//   R8-R11 invariants showed per-block fill/drain + A re-stage as the residue:
//   time pinned 76-82us while occupancy/L2/LDS-traffic/sink-proofing each
//   varied). Grid 1280 = exactly 5 blocks/CU. Verified conventions unchanged.
// Fallback to the verified R2 path if ws_size < ~24 MB.
// ---------------------------------------------------------------------------

#define DIM 512
#define M_Q 1024
#define P_TM 4096
#define P_XT 16384
#define P_ALL (P_TM + P_XT)          // 20480
#define NROWS_ALL (M_Q + P_ALL)      // 21504

#define BK 64
#define NSTEP (DIM / BK)             // 8
#define NSTRIP 4                     // n-chunks per block
#define CHUNK 64
#define NCHUNK_TM (P_TM / CHUNK)     // 64
#define NCHUNK_TOT (P_ALL / CHUNK)   // 320
#define BIGF 3.402823466e38f

typedef __bf16 bf16x8 __attribute__((ext_vector_type(8)));
typedef float f32x4 __attribute__((ext_vector_type(4)));
typedef unsigned short u16x8 __attribute__((ext_vector_type(8)));

__device__ __forceinline__ unsigned short f2bf(float f) {
    unsigned int u = __float_as_uint(f);
    unsigned int r = (u + 0x7fffu + ((u >> 16) & 1u)) >> 16;
    return (unsigned short)r;
}

__device__ __forceinline__ void merge1(float v, float& d1, float& d2) {
    if (v < d1) { d2 = d1; d1 = v; }
    else if (v < d2) { d2 = v; }
}

__device__ __forceinline__ void top2_shfl16(float& d1, float& d2) {
    #pragma unroll
    for (int off = 1; off < 16; off <<= 1) {
        float o1 = __shfl_xor(d1, off);
        float o2 = __shfl_xor(d2, off);
        float n1 = fminf(d1, o1);
        float n2 = fminf(fmaxf(d1, o1), fminf(d2, o2));
        d1 = n1; d2 = n2;
    }
}

__device__ __forceinline__ void async_copy16(const void* g, void* l) {
    __builtin_amdgcn_global_load_lds(
        (const __attribute__((address_space(1))) void*)g,
        (__attribute__((address_space(3))) void*)l,
        16, 0, 0);
}

// ---------------------------------------------------------------------------
// Pass 1: f32 -> bf16 + squared norms. One wave per row (512 elems, 8/lane).
// ---------------------------------------------------------------------------
__global__ __launch_bounds__(256) void convert_norms_kernel(
    const float* __restrict__ Q, const float* __restrict__ TMat,
    const float* __restrict__ XT,
    unsigned short* __restrict__ Qb, unsigned short* __restrict__ Db,
    float* __restrict__ qn, float* __restrict__ dn)
{
    const int wid = threadIdx.x >> 6;
    const int lane = threadIdx.x & 63;
    const int row = blockIdx.x * 4 + wid;

    const float* src;
    unsigned short* dst;
    float* ndst;
    if (row < M_Q) {
        src = Q + (size_t)row * DIM; dst = Qb + (size_t)row * DIM; ndst = qn + row;
    } else {
        int r = row - M_Q;
        src = (row < M_Q + P_TM) ? (TMat + (size_t)r * DIM)
                                 : (XT + (size_t)(row - (M_Q + P_TM)) * DIM);
        dst = Db + (size_t)r * DIM; ndst = dn + r;
    }

    const float* p = src + lane * 8;
    float4 v0 = *(const float4*)p;
    float4 v1 = *(const float4*)(p + 4);
    float s = v0.x*v0.x + v0.y*v0.y + v0.z*v0.z + v0.w*v0.w
            + v1.x*v1.x + v1.y*v1.y + v1.z*v1.z + v1.w*v1.w;

    u16x8 o;
    o[0]=f2bf(v0.x); o[1]=f2bf(v0.y); o[2]=f2bf(v0.z); o[3]=f2bf(v0.w);
    o[4]=f2bf(v1.x); o[5]=f2bf(v1.y); o[6]=f2bf(v1.z); o[7]=f2bf(v1.w);
    *(u16x8*)(dst + lane * 8) = o;

    #pragma unroll
    for (int off = 32; off > 0; off >>= 1) s += __shfl_xor(s, off);
    if (lane == 0) *ndst = s;
}

// ---------------------------------------------------------------------------
// Pass 2: A-in-registers, B-strip-streaming MFMA distance + per-chunk top-2.
// Grid 1280 blocks x 256 threads. bid: xcd=bid&7; j=bid>>3; mblk=j&15;
// strip=(j>>4)*8+xcd (0..79). Block covers 64 m-rows x 4 n-chunks (256 rows).
// A: wave wid owns rows [mBase+wid*16,+16); frag q (q=0..15 => k=q*32+h*8)
//    lives in aReg[q] (loaded once from L2-hot Qb).
// B: LDS [64][64] bf16 per buffer, 16B chunk c of row r at c^(r&7); staged
//    via gload_lds with inverse-swizzled source (verified R3/R4/R11).
// K-loop: 32 steps (4 chunks x 8), stage (next step) -> compute -> barrier.
// ---------------------------------------------------------------------------
__global__ __launch_bounds__(256, 3) void dist_mfma_kernel(
    const unsigned short* __restrict__ Qb,   // [M_Q][DIM] bf16
    const unsigned short* __restrict__ Db,   // [P_ALL][DIM] bf16
    const float* __restrict__ qn,            // [M_Q]
    const float* __restrict__ dn,            // [P_ALL]
    float* __restrict__ partial)             // [M_Q][NCHUNK_TOT][2]
{
    __shared__ __align__(16) unsigned short Bs[2][64 * 64];  // 2 x 8 KB

    const int tid  = threadIdx.x;
    const int lane = tid & 63;
    const int wid  = tid >> 6;          // 0..3
    const int r15  = lane & 15;
    const int h    = lane >> 4;         // 0..3

    // --- XCD-aware remap ---
    const int bid   = blockIdx.x;        // 0..1279
    const int xcd   = bid & 7;
    const int j     = bid >> 3;          // 0..159
    const int mblk  = j & 15;
    const int strip = ((j >> 4) << 3) + xcd;   // 0..79
    const int mBase = mblk * 64;
    const int nRow0 = strip * (NSTRIP * 64);   // first dataset row of strip

    // --- A panel into registers: frag q -> row mBase+wid*16+r15, k=q*32+h*8
    const unsigned short* gA = Qb + (size_t)(mBase + wid * 16 + r15) * DIM + h * 8;
    bf16x8 aReg[16];
    #pragma unroll
    for (int q = 0; q < 16; ++q)
        aReg[q] = *(const bf16x8*)(gA + q * 32);

    // --- B staging (verified R11 mapping): slab s covers rows [s*8,+8) ---
    const int rowS0 = wid * 8 + (lane >> 3);          // rows 0..31 (s = wid)
    const int clog  = (lane & 7) ^ ((lane >> 3) & 7); // inverse swizzle
    const unsigned short* srcB0 = Db + (size_t)(nRow0 + rowS0) * DIM + clog * 8;
    const unsigned short* srcB1 = srcB0 + (size_t)32 * DIM;   // rows 32..63
    const int ldsOff0 = wid * 1024;         // byte offset (wave-uniform)
    const int ldsOff1 = (4 + wid) * 1024;

    // --- B ds_read addresses (ushort idx; verified) ---
    const int bB0 = r15 * 64 + (((h    ) ^ (r15 & 7)) << 3);
    const int bB1 = r15 * 64 + (((4 | h) ^ (r15 & 7)) << 3);

    // --- prologue: stage (c=0, t=0) into buffer 0 ---
    async_copy16(srcB0, (char*)&Bs[0][0] + ldsOff0);
    async_copy16(srcB1, (char*)&Bs[0][0] + ldsOff1);
    __syncthreads();

    for (int c = 0; c < NSTRIP; ++c) {
        const unsigned short* sB0 = srcB0 + (size_t)c * 64 * DIM;
        const unsigned short* sB1 = srcB1 + (size_t)c * 64 * DIM;

        f32x4 acc0, acc1, acc2, acc3;
        #pragma unroll
        for (int i = 0; i < 4; ++i) { acc0[i]=0.f; acc1[i]=0.f; acc2[i]=0.f; acc3[i]=0.f; }

        #pragma unroll
        for (int t = 0; t < NSTEP; ++t) {
            const int buf = t & 1;          // compile-time after unroll

            // stage next step (fire-and-forget; cannot be sunk)
            if (!(c == NSTRIP - 1 && t == NSTEP - 1)) {
                const unsigned short* nb0 =
                    (t < NSTEP - 1) ? (sB0 + (t + 1) * BK) : (sB0 + (size_t)64 * DIM);
                const unsigned short* nb1 =
                    (t < NSTEP - 1) ? (sB1 + (t + 1) * BK) : (sB1 + (size_t)64 * DIM);
                async_copy16(nb0, (char*)&Bs[buf ^ 1][0] + ldsOff0);
                async_copy16(nb1, (char*)&Bs[buf ^ 1][0] + ldsOff1);
            }

            // kh = 0: aReg[2t]
            {
                bf16x8 b0 = *(const bf16x8*)(&Bs[buf][bB0]);
                bf16x8 b1 = *(const bf16x8*)(&Bs[buf][bB0 + 1024]);
                bf16x8 b2 = *(const bf16x8*)(&Bs[buf][bB0 + 2048]);
                bf16x8 b3 = *(const bf16x8*)(&Bs[buf][bB0 + 3072]);
                acc0 = __builtin_amdgcn_mfma_f32_16x16x32_bf16(aReg[2*t],   b0, acc0, 0, 0, 0);
                acc1 = __builtin_amdgcn_mfma_f32_16x16x32_bf16(aReg[2*t],   b1, acc1, 0, 0, 0);
                acc2 = __builtin_amdgcn_mfma_f32_16x16x32_bf16(aReg[2*t],   b2, acc2, 0, 0, 0);
                acc3 = __builtin_amdgcn_mfma_f32_16x16x32_bf16(aReg[2*t],   b3, acc3, 0, 0, 0);
            }
            // kh = 1: aReg[2t+1]
            {
                bf16x8 b0 = *(const bf16x8*)(&Bs[buf][bB1]);
                bf16x8 b1 = *(const bf16x8*)(&Bs[buf][bB1 + 1024]);
                bf16x8 b2 = *(const bf16x8*)(&Bs[buf][bB1 + 2048]);
                bf16x8 b3 = *(const bf16x8*)(&Bs[buf][bB1 + 3072]);
                acc0 = __builtin_amdgcn_mfma_f32_16x16x32_bf16(aReg[2*t+1], b0, acc0, 0, 0, 0);
                acc1 = __builtin_amdgcn_mfma_f32_16x16x32_bf16(aReg[2*t+1], b1, acc1, 0, 0, 0);
                acc2 = __builtin_amdgcn_mfma_f32_16x16x32_bf16(aReg[2*t+1], b2, acc2, 0, 0, 0);
                acc3 = __builtin_amdgcn_mfma_f32_16x16x32_bf16(aReg[2*t+1], b3, acc3, 0, 0, 0);
            }

            __syncthreads();   // vmcnt+lgkm drain: next staged tile landed,
                               // all waves done reading Bs[buf]
        }

        // --- epilogue for n-chunk (strip*NSTRIP + c) ---
        {
            const int nchunk = strip * NSTRIP + c;
            const int nBase  = nchunk * 64;
            const int rbase  = mBase + wid * 16 + (h << 2);
            float q2[4];
            #pragma unroll
            for (int r = 0; r < 4; ++r) q2[r] = qn[rbase + r];

            float d1[4], d2[4];
            #pragma unroll
            for (int r = 0; r < 4; ++r) { d1[r] = BIGF; d2[r] = BIGF; }

            #pragma unroll
            for (int nt = 0; nt < 4; ++nt) {
                float dd = dn[nBase + nt * 16 + r15];
                const f32x4& a = (nt == 0) ? acc0 : (nt == 1) ? acc1
                                : (nt == 2) ? acc2 : acc3;
                #pragma unroll
                for (int r = 0; r < 4; ++r) {
                    float sq = q2[r] + dd - 2.0f * a[r];
                    sq = fmaxf(sq, 0.0f);
                    merge1(sq, d1[r], d2[r]);
                }
            }

            #pragma unroll
            for (int r = 0; r < 4; ++r) top2_shfl16(d1[r], d2[r]);

            if (r15 == 0) {
                #pragma unroll
                for (int r = 0; r < 4; ++r) {
                    size_t base = ((size_t)(rbase + r) * NCHUNK_TOT + nchunk) * 2;
                    partial[base]     = d1[r];
                    partial[base + 1] = d2[r];
                }
            }
        }
    }
}

// ---------------------------------------------------------------------------
// Pass 3: merge per-chunk top-2 partials (one wave per query).
// ---------------------------------------------------------------------------
__global__ __launch_bounds__(256) void reduce_top2_kernel(
    const float* __restrict__ partial, float* __restrict__ fin)
{
    const int wid  = threadIdx.x >> 6;
    const int lane = threadIdx.x & 63;
    const int m = blockIdx.x * 4 + wid;
    const float* p = partial + (size_t)m * (NCHUNK_TOT * 2);

    float2 v = *(const float2*)(p + 2 * lane);
    float a1 = fminf(v.x, v.y), a2 = fmaxf(v.x, v.y);
    #pragma unroll
    for (int off = 32; off > 0; off >>= 1) {
        float o1 = __shfl_xor(a1, off);
        float o2 = __shfl_xor(a2, off);
        float n1 = fminf(a1, o1);
        float n2 = fminf(fmaxf(a1, o1), fminf(a2, o2));
        a1 = n1; a2 = n2;
    }

    const float* px = p + 2 * NCHUNK_TM + lane * 8;
    float4 w0 = *(const float4*)px;
    float4 w1 = *(const float4*)(px + 4);
    float b1 = BIGF, b2 = BIGF;
    merge1(w0.x, b1, b2); merge1(w0.y, b1, b2);
    merge1(w0.z, b1, b2); merge1(w0.w, b1, b2);
    merge1(w1.x, b1, b2); merge1(w1.y, b1, b2);
    merge1(w1.z, b1, b2); merge1(w1.w, b1, b2);
    #pragma unroll
    for (int off = 32; off > 0; off >>= 1) {
        float o1 = __shfl_xor(b1, off);
        float o2 = __shfl_xor(b2, off);
        float n1 = fminf(b1, o1);
        float n2 = fminf(fmaxf(b1, o1), fminf(b2, o2));
        b1 = n1; b2 = n2;
    }

    if (lane == 0) {
        fin[m]           = sqrtf(a1);
        fin[M_Q + m]     = sqrtf(a2);
        fin[2*M_Q + m]   = sqrtf(b1);
        fin[3*M_Q + m]   = sqrtf(b2);
    }
}

// ---------------------------------------------------------------------------
// Pass 4: stats. Both percentile arrays sorted in ONE bitonic pass.
// ---------------------------------------------------------------------------
__global__ __launch_bounds__(1024) void stats_kernel(
    const float* __restrict__ fin, float* __restrict__ out)
{
    __shared__ float s0[1024];
    __shared__ float s1a[1024];
    __shared__ float red[16][6];
    const int t = threadIdx.x;

    float m1 = fin[t];
    float m2 = fin[1024 + t];
    float s1 = fin[2048 + t];
    float s2 = fin[3072 + t];

    const float T = 1.0f / 3.0f;
    float v[6];
    v[0] = (m1 < T * s1 && m1 < T * m2) ? 1.0f : 0.0f;
    v[1] = (s1 < T * m1 && s1 < T * s2) ? 1.0f : 0.0f;
    v[2] = m1; v[3] = s1; v[4] = m2; v[5] = s2;

    #pragma unroll
    for (int off = 32; off > 0; off >>= 1)
        #pragma unroll
        for (int i = 0; i < 6; ++i) v[i] += __shfl_xor(v[i], off);

    int lane = t & 63, wid = t >> 6;
    if (lane == 0) {
        #pragma unroll
        for (int i = 0; i < 6; ++i) red[wid][i] = v[i];
    }
    __syncthreads();
    if (t == 0) {
        float a[6] = {0, 0, 0, 0, 0, 0};
        for (int w = 0; w < 16; ++w)
            for (int i = 0; i < 6; ++i) a[i] += red[w][i];
        out[0] = a[0];
        out[1] = a[1];
        out[2] = a[2] / 1024.0f;
        out[3] = a[3] / 1024.0f;
        out[4] = a[4] / 1024.0f;
        out[5] = a[5] / 1024.0f;
    }

    s0[t]  = m1;
    s1a[t] = s1;
    __syncthreads();

    for (int k = 2; k <= 1024; k <<= 1) {
        for (int jj = k >> 1; jj > 0; jj >>= 1) {
            int ixj = t ^ jj;
            if (ixj > t) {
                bool up = ((t & k) == 0);
                float a = s0[t], b = s0[ixj];
                if ((a > b) == up) { s0[t] = b; s0[ixj] = a; }
                float c = s1a[t], d = s1a[ixj];
                if ((c > d) == up) { s1a[t] = d; s1a[ixj] = c; }
            }
            __syncthreads();
        }
    }

    if (t < 5) {
        const float P[5] = {10.f, 25.f, 50.f, 75.f, 90.f};
        float q = P[t] * 1023.0f / 100.0f;
        int lo = (int)q;
        float fr = q - (float)lo;
        out[6 + t]  = s0[lo]  + fr * (s0[lo + 1]  - s0[lo]);
        out[11 + t] = s1a[lo] + fr * (s1a[lo + 1] - s1a[lo]);
    }
}

// ---------------------------------------------------------------------------
// Fallback path (verified R2 kernels) — used only if ws_size is too small.
// ---------------------------------------------------------------------------
__global__ __launch_bounds__(256) void norms_kernel_fb(
    const float* __restrict__ src, float* __restrict__ dst, int nrows)
{
    int wid = threadIdx.x >> 6;
    int lane = threadIdx.x & 63;
    int row = blockIdx.x * 4 + wid;
    if (row >= nrows) return;
    const float* p = src + (size_t)row * DIM + lane * 8;
    float4 v0 = *(const float4*)p;
    float4 v1 = *(const float4*)(p + 4);
    float s = v0.x*v0.x + v0.y*v0.y + v0.z*v0.z + v0.w*v0.w
            + v1.x*v1.x + v1.y*v1.y + v1.z*v1.z + v1.w*v1.w;
    #pragma unroll
    for (int off = 32; off > 0; off >>= 1) s += __shfl_xor(s, off);
    if (lane == 0) dst[row] = s;
}

__global__ __launch_bounds__(256) void dist_top2_kernel_fb(
    const float* __restrict__ Q, const float* __restrict__ Dset,
    const float* __restrict__ qn, const float* __restrict__ dn,
    float* __restrict__ partial, int chunkGlobalOffset)
{
    __shared__ __align__(16) unsigned short As[64][40];
    __shared__ __align__(16) unsigned short Bs[64][40];

    const int tid  = threadIdx.x;
    const int lane = tid & 63;
    const int wid  = tid >> 6;
    const int mBase = blockIdx.y * 64;
    const int nBase = blockIdx.x * 64;

    const int srow = tid >> 2;
    const int skc  = (tid & 3) * 8;

    const float* qrow = Q    + (size_t)(mBase + srow) * DIM + skc;
    const float* drow = Dset + (size_t)(nBase + srow) * DIM + skc;

    f32x4 acc[4];
    #pragma unroll
    for (int nt = 0; nt < 4; ++nt)
        #pragma unroll
        for (int i = 0; i < 4; ++i) acc[nt][i] = 0.0f;

    const int frow = lane & 15;
    const int fk   = (lane >> 4) * 8;

    for (int ks = 0; ks < DIM; ks += 32) {
        float4 a0 = *(const float4*)(qrow + ks);
        float4 a1 = *(const float4*)(qrow + ks + 4);
        float4 b0 = *(const float4*)(drow + ks);
        float4 b1 = *(const float4*)(drow + ks + 4);

        u16x8 va, vb;
        va[0]=f2bf(a0.x); va[1]=f2bf(a0.y); va[2]=f2bf(a0.z); va[3]=f2bf(a0.w);
        va[4]=f2bf(a1.x); va[5]=f2bf(a1.y); va[6]=f2bf(a1.z); va[7]=f2bf(a1.w);
        vb[0]=f2bf(b0.x); vb[1]=f2bf(b0.y); vb[2]=f2bf(b0.z); vb[3]=f2bf(b0.w);
        vb[4]=f2bf(b1.x); vb[5]=f2bf(b1.y); vb[6]=f2bf(b1.z); vb[7]=f2bf(b1.w);

        *(u16x8*)(&As[srow][skc]) = va;
        *(u16x8*)(&Bs[srow][skc]) = vb;
        __syncthreads();

        bf16x8 af = *(const bf16x8*)(&As[wid * 16 + frow][fk]);
        #pragma unroll
        for (int nt = 0; nt < 4; ++nt) {
            bf16x8 bf = *(const bf16x8*)(&Bs[nt * 16 + frow][fk]);
            acc[nt] = __builtin_amdgcn_mfma_f32_16x16x32_bf16(af, bf, acc[nt], 0, 0, 0);
        }
        __syncthreads();
    }

    const int rbase = mBase + wid * 16 + ((lane >> 4) << 2);
    float q2[4];
    #pragma unroll
    for (int r = 0; r < 4; ++r) q2[r] = qn[rbase + r];

    float d1[4], d2[4];
    #pragma unroll
    for (int r = 0; r < 4; ++r) { d1[r] = BIGF; d2[r] = BIGF; }

    #pragma unroll
    for (int nt = 0; nt < 4; ++nt) {
        float dd = dn[nBase + nt * 16 + (lane & 15)];
        #pragma unroll
        for (int r = 0; r < 4; ++r) {
            float sq = q2[r] + dd - 2.0f * acc[nt][r];
            sq = fmaxf(sq, 0.0f);
            merge1(sq, d1[r], d2[r]);
        }
    }

    #pragma unroll
    for (int r = 0; r < 4; ++r) top2_shfl16(d1[r], d2[r]);

    if ((lane & 15) == 0) {
        int chunkG = chunkGlobalOffset + blockIdx.x;
        #pragma unroll
        for (int r = 0; r < 4; ++r) {
            size_t base = ((size_t)(rbase + r) * NCHUNK_TOT + chunkG) * 2;
            partial[base]     = d1[r];
            partial[base + 1] = d2[r];
        }
    }
}

// ---------------------------------------------------------------------------
extern "C" void kernel_launch(void* const* d_in, const int* in_sizes, int n_in,
                              void* d_out, int out_size, void* d_ws, size_t ws_size,
                              hipStream_t stream) {
    const float* Q  = (const float*)d_in[0];
    const float* TM = (const float*)d_in[1];
    const float* XT = (const float*)d_in[2];
    float* out = (float*)d_out;

    const size_t needMain =
        (size_t)M_Q * DIM * 2 + (size_t)P_ALL * DIM * 2 +
        4 * ((size_t)M_Q + P_ALL + (size_t)M_Q * NCHUNK_TOT * 2 + 4 * M_Q);

    if (ws_size >= needMain) {
        char* w = (char*)d_ws;
        unsigned short* Qb = (unsigned short*)w;
        unsigned short* Db = (unsigned short*)(w + (size_t)M_Q * DIM * 2);
        float* qn = (float*)(w + (size_t)M_Q * DIM * 2 + (size_t)P_ALL * DIM * 2);
        float* dn = qn + M_Q;
        float* partial = dn + P_ALL;
        float* fin = partial + (size_t)M_Q * NCHUNK_TOT * 2;

        convert_norms_kernel<<<dim3(NROWS_ALL / 4), 256, 0, stream>>>(
            Q, TM, XT, Qb, Db, qn, dn);
        dist_mfma_kernel<<<dim3((NCHUNK_TOT / NSTRIP) * (M_Q / 64)), 256, 0, stream>>>(
            Qb, Db, qn, dn, partial);
        reduce_top2_kernel<<<dim3(M_Q / 4), 256, 0, stream>>>(partial, fin);
        stats_kernel<<<dim3(1), 1024, 0, stream>>>(fin, out);
    } else {
        float* ws = (float*)d_ws;
        float* qn = ws;
        float* dn = ws + M_Q;
        float* partial = dn + P_ALL;
        float* fin = partial + (size_t)M_Q * NCHUNK_TOT * 2;

        norms_kernel_fb<<<dim3(M_Q / 4),  256, 0, stream>>>(Q,  qn, M_Q);
        norms_kernel_fb<<<dim3(P_TM / 4), 256, 0, stream>>>(TM, dn, P_TM);
        norms_kernel_fb<<<dim3(P_XT / 4), 256, 0, stream>>>(XT, dn + P_TM, P_XT);
        dist_top2_kernel_fb<<<dim3(P_TM / 64, M_Q / 64), 256, 0, stream>>>(
            Q, TM, qn, dn, partial, 0);
        dist_top2_kernel_fb<<<dim3(P_XT / 64, M_Q / 64), 256, 0, stream>>>(
            Q, XT, qn, dn + P_TM, partial, NCHUNK_TM);
        reduce_top2_kernel<<<dim3(M_Q / 4), 256, 0, stream>>>(partial, fin);
        stats_kernel<<<dim3(1), 1024, 0, stream>>>(fin, out);
    }
}

// Round 13
// 100.916 us; speedup vs baseline: 1.1130x; 1.1130x over previous
//
#include <hip/hip_runtime.h>
#include <hip/hip_bf16.h>

// ---------------------------------------------------------------------------
// LearnedMeans: 2-NN distances + statistics. R13 = R11 with T4 counted-vmcnt
// sync (the ONLY change -- everything else byte-identical to passing R11):
//   R8-R12 invariant (time 76-82us, MfmaUtil 8-11% across occupancy/L2/LDS/
//   staging variants) is explained by __syncthreads() semantics: it drains
//   vmcnt(0) EVERY K-step, so "in-flight" staging loads are waited to
//   completion each step -- full global->LDS round trip serialized, ~8 MFMAs
//   to hide it. T4 fix (m218: counted-vs-drain0 = +38..73%): raw s_barrier +
//   inline-asm s_waitcnt vmcnt(4), 2-step stage lead. Loads for t+2 stay in
//   flight ACROSS both barriers; each step waits only for the stage issued a
//   full step earlier (mostly landed).
//   Per step: compute(buf) -> s_barrier -> stage(t+2 -> same buf) ->
//             vmcnt(4) -> sched_barrier(0) -> s_barrier.
// Fallback to the verified R2 path if ws_size < ~24 MB.
// ---------------------------------------------------------------------------

#define DIM 512
#define M_Q 1024
#define P_TM 4096
#define P_XT 16384
#define P_ALL (P_TM + P_XT)          // 20480
#define NROWS_ALL (M_Q + P_ALL)      // 21504

#define BK 64
#define NSTEP (DIM / BK)             // 8
#define CHUNK 64
#define NCHUNK_TM (P_TM / CHUNK)     // 64
#define NCHUNK_TOT (P_ALL / CHUNK)   // 320
#define BIGF 3.402823466e38f

typedef __bf16 bf16x8 __attribute__((ext_vector_type(8)));
typedef float f32x4 __attribute__((ext_vector_type(4)));
typedef unsigned short u16x8 __attribute__((ext_vector_type(8)));

__device__ __forceinline__ unsigned short f2bf(float f) {
    unsigned int u = __float_as_uint(f);
    unsigned int r = (u + 0x7fffu + ((u >> 16) & 1u)) >> 16;
    return (unsigned short)r;
}

__device__ __forceinline__ void merge1(float v, float& d1, float& d2) {
    if (v < d1) { d2 = d1; d1 = v; }
    else if (v < d2) { d2 = v; }
}

__device__ __forceinline__ void top2_shfl16(float& d1, float& d2) {
    #pragma unroll
    for (int off = 1; off < 16; off <<= 1) {
        float o1 = __shfl_xor(d1, off);
        float o2 = __shfl_xor(d2, off);
        float n1 = fminf(d1, o1);
        float n2 = fminf(fmaxf(d1, o1), fminf(d2, o2));
        d1 = n1; d2 = n2;
    }
}

__device__ __forceinline__ void async_copy16(const void* g, void* l) {
    __builtin_amdgcn_global_load_lds(
        (const __attribute__((address_space(1))) void*)g,
        (__attribute__((address_space(3))) void*)l,
        16, 0, 0);
}

// ---------------------------------------------------------------------------
// Pass 1: f32 -> bf16 + squared norms. One wave per row (512 elems, 8/lane).
// ---------------------------------------------------------------------------
__global__ __launch_bounds__(256) void convert_norms_kernel(
    const float* __restrict__ Q, const float* __restrict__ TMat,
    const float* __restrict__ XT,
    unsigned short* __restrict__ Qb, unsigned short* __restrict__ Db,
    float* __restrict__ qn, float* __restrict__ dn)
{
    const int wid = threadIdx.x >> 6;
    const int lane = threadIdx.x & 63;
    const int row = blockIdx.x * 4 + wid;

    const float* src;
    unsigned short* dst;
    float* ndst;
    if (row < M_Q) {
        src = Q + (size_t)row * DIM; dst = Qb + (size_t)row * DIM; ndst = qn + row;
    } else {
        int r = row - M_Q;
        src = (row < M_Q + P_TM) ? (TMat + (size_t)r * DIM)
                                 : (XT + (size_t)(row - (M_Q + P_TM)) * DIM);
        dst = Db + (size_t)r * DIM; ndst = dn + r;
    }

    const float* p = src + lane * 8;
    float4 v0 = *(const float4*)p;
    float4 v1 = *(const float4*)(p + 4);
    float s = v0.x*v0.x + v0.y*v0.y + v0.z*v0.z + v0.w*v0.w
            + v1.x*v1.x + v1.y*v1.y + v1.z*v1.z + v1.w*v1.w;

    u16x8 o;
    o[0]=f2bf(v0.x); o[1]=f2bf(v0.y); o[2]=f2bf(v0.z); o[3]=f2bf(v0.w);
    o[4]=f2bf(v1.x); o[5]=f2bf(v1.y); o[6]=f2bf(v1.z); o[7]=f2bf(v1.w);
    *(u16x8*)(dst + lane * 8) = o;

    #pragma unroll
    for (int off = 32; off > 0; off >>= 1) s += __shfl_xor(s, off);
    if (lane == 0) *ndst = s;
}

// ---------------------------------------------------------------------------
// Pass 2: 64x64-tile MFMA distance + per-chunk top-2, double-buffered
// global_load_lds staging with COUNTED vmcnt (T4) -- no vmcnt(0) in loop.
// LDS layout / swizzle / staging maps / ds_read addrs: verified R11.
// ---------------------------------------------------------------------------
__global__ __launch_bounds__(256, 5) void dist_mfma_kernel(
    const unsigned short* __restrict__ Qb,   // [M_Q][DIM] bf16
    const unsigned short* __restrict__ Db,   // [P_ALL][DIM] bf16
    const float* __restrict__ qn,            // [M_Q]
    const float* __restrict__ dn,            // [P_ALL]
    float* __restrict__ partial)             // [M_Q][NCHUNK_TOT][2]
{
    __shared__ __align__(16) unsigned short As[2][64 * 64];  // 2 x 8 KB
    __shared__ __align__(16) unsigned short Bs[2][64 * 64];  // 2 x 8 KB

    const int tid  = threadIdx.x;
    const int lane = tid & 63;
    const int wid  = tid >> 6;          // 0..3
    const int r15  = lane & 15;
    const int h    = lane >> 4;         // 0..3

    // --- XCD-aware sweep remap (verified R9) ---
    const int bid    = blockIdx.x;       // 0..5119
    const int xcd    = bid & 7;
    const int j      = bid >> 3;         // 0..639
    const int mblk   = j & 15;
    const int nchunk = ((j >> 4) << 3) + xcd;   // 0..319
    const int mBase  = mblk * 64;
    const int nBase  = nchunk * 64;

    // --- gload_lds staging (verified R11): slabs s0 = wid, s1 = 4+wid ---
    const int rowS0 = wid * 8 + (lane >> 3);          // rows 0..31
    const int clog  = (lane & 7) ^ ((lane >> 3) & 7); // inverse swizzle
    const unsigned short* srcA0 = Qb + (size_t)(mBase + rowS0) * DIM + clog * 8;
    const unsigned short* srcA1 = srcA0 + (size_t)32 * DIM;   // rows 32..63
    const unsigned short* srcB0 = Db + (size_t)(nBase + rowS0) * DIM + clog * 8;
    const unsigned short* srcB1 = srcB0 + (size_t)32 * DIM;
    const int ldsOff0 = wid * 1024;         // byte offset, wave-uniform
    const int ldsOff1 = (4 + wid) * 1024;

    // --- ds_read addresses (ushort idx; verified R8/R9/R11) ---
    const int aA0 = (wid * 16 + r15) * 64 + (((h    ) ^ (r15 & 7)) << 3);
    const int aA1 = (wid * 16 + r15) * 64 + (((4 | h) ^ (r15 & 7)) << 3);
    const int bB0 = r15 * 64 + (((h    ) ^ (r15 & 7)) << 3);
    const int bB1 = r15 * 64 + (((4 | h) ^ (r15 & 7)) << 3);

    f32x4 acc0, acc1, acc2, acc3;
    #pragma unroll
    for (int i = 0; i < 4; ++i) { acc0[i]=0.f; acc1[i]=0.f; acc2[i]=0.f; acc3[i]=0.f; }

    // --- prologue: stage steps 0 and 1; wait only for step 0 (vmcnt(4)) ---
    async_copy16(srcA0, (char*)&As[0][0] + ldsOff0);
    async_copy16(srcA1, (char*)&As[0][0] + ldsOff1);
    async_copy16(srcB0, (char*)&Bs[0][0] + ldsOff0);
    async_copy16(srcB1, (char*)&Bs[0][0] + ldsOff1);
    async_copy16(srcA0 + BK, (char*)&As[1][0] + ldsOff0);
    async_copy16(srcA1 + BK, (char*)&As[1][0] + ldsOff1);
    async_copy16(srcB0 + BK, (char*)&Bs[1][0] + ldsOff0);
    async_copy16(srcB1 + BK, (char*)&Bs[1][0] + ldsOff1);
    asm volatile("s_waitcnt vmcnt(4)" ::: "memory");   // stage(0) landed
    __builtin_amdgcn_sched_barrier(0);
    __builtin_amdgcn_s_barrier();                      // collective: buf0 ready
    __builtin_amdgcn_sched_barrier(0);

    #pragma unroll
    for (int t = 0; t < NSTEP; ++t) {
        const int cur = t & 1;

        // ---- compute step t from buf[cur] (stage(t+1) still in flight) ----
        // kh = 0
        {
            bf16x8 af = *(const bf16x8*)(&As[cur][aA0]);
            bf16x8 b0 = *(const bf16x8*)(&Bs[cur][bB0]);
            bf16x8 b1 = *(const bf16x8*)(&Bs[cur][bB0 + 1024]);
            bf16x8 b2 = *(const bf16x8*)(&Bs[cur][bB0 + 2048]);
            bf16x8 b3 = *(const bf16x8*)(&Bs[cur][bB0 + 3072]);
            acc0 = __builtin_amdgcn_mfma_f32_16x16x32_bf16(af, b0, acc0, 0, 0, 0);
            acc1 = __builtin_amdgcn_mfma_f32_16x16x32_bf16(af, b1, acc1, 0, 0, 0);
            acc2 = __builtin_amdgcn_mfma_f32_16x16x32_bf16(af, b2, acc2, 0, 0, 0);
            acc3 = __builtin_amdgcn_mfma_f32_16x16x32_bf16(af, b3, acc3, 0, 0, 0);
        }
        // kh = 1
        {
            bf16x8 af = *(const bf16x8*)(&As[cur][aA1]);
            bf16x8 b0 = *(const bf16x8*)(&Bs[cur][bB1]);
            bf16x8 b1 = *(const bf16x8*)(&Bs[cur][bB1 + 1024]);
            bf16x8 b2 = *(const bf16x8*)(&Bs[cur][bB1 + 2048]);
            bf16x8 b3 = *(const bf16x8*)(&Bs[cur][bB1 + 3072]);
            acc0 = __builtin_amdgcn_mfma_f32_16x16x32_bf16(af, b0, acc0, 0, 0, 0);
            acc1 = __builtin_amdgcn_mfma_f32_16x16x32_bf16(af, b1, acc1, 0, 0, 0);
            acc2 = __builtin_amdgcn_mfma_f32_16x16x32_bf16(af, b2, acc2, 0, 0, 0);
            acc3 = __builtin_amdgcn_mfma_f32_16x16x32_bf16(af, b3, acc3, 0, 0, 0);
        }

        // all waves done READING buf[cur] (ds_read results are lgkmcnt-waited
        // before their MFMA uses above, so data is in registers here)
        __builtin_amdgcn_s_barrier();
        __builtin_amdgcn_sched_barrier(0);

        // ---- restage buf[cur] with step t+2; wait only for stage(t+1) ----
        if (t + 2 < NSTEP) {
            const int ks = (t + 2) * BK;
            async_copy16(srcA0 + ks, (char*)&As[cur][0] + ldsOff0);
            async_copy16(srcA1 + ks, (char*)&As[cur][0] + ldsOff1);
            async_copy16(srcB0 + ks, (char*)&Bs[cur][0] + ldsOff0);
            async_copy16(srcB1 + ks, (char*)&Bs[cur][0] + ldsOff1);
            asm volatile("s_waitcnt vmcnt(4)" ::: "memory");  // stage(t+1) landed
        } else if (t + 1 < NSTEP) {
            asm volatile("s_waitcnt vmcnt(0)" ::: "memory");  // tail: stage(t+1)
        }
        __builtin_amdgcn_sched_barrier(0);
        __builtin_amdgcn_s_barrier();   // collective: buf[cur^1] ready for t+1
        __builtin_amdgcn_sched_barrier(0);
    }

    // --- epilogue (verified conventions): row=rbase+r, col=nBase+nt*16+r15 ---
    const int rbase = mBase + wid * 16 + (h << 2);
    float q2[4];
    #pragma unroll
    for (int r = 0; r < 4; ++r) q2[r] = qn[rbase + r];

    float d1[4], d2[4];
    #pragma unroll
    for (int r = 0; r < 4; ++r) { d1[r] = BIGF; d2[r] = BIGF; }

    #pragma unroll
    for (int nt = 0; nt < 4; ++nt) {
        float dd = dn[nBase + nt * 16 + r15];
        const f32x4& a = (nt == 0) ? acc0 : (nt == 1) ? acc1 : (nt == 2) ? acc2 : acc3;
        #pragma unroll
        for (int r = 0; r < 4; ++r) {
            float sq = q2[r] + dd - 2.0f * a[r];
            sq = fmaxf(sq, 0.0f);
            merge1(sq, d1[r], d2[r]);
        }
    }

    #pragma unroll
    for (int r = 0; r < 4; ++r) top2_shfl16(d1[r], d2[r]);

    if (r15 == 0) {
        #pragma unroll
        for (int r = 0; r < 4; ++r) {
            size_t base = ((size_t)(rbase + r) * NCHUNK_TOT + nchunk) * 2;
            partial[base]     = d1[r];
            partial[base + 1] = d2[r];
        }
    }
}

// ---------------------------------------------------------------------------
// Pass 3: merge per-chunk top-2 partials (one wave per query).
// ---------------------------------------------------------------------------
__global__ __launch_bounds__(256) void reduce_top2_kernel(
    const float* __restrict__ partial, float* __restrict__ fin)
{
    const int wid  = threadIdx.x >> 6;
    const int lane = threadIdx.x & 63;
    const int m = blockIdx.x * 4 + wid;
    const float* p = partial + (size_t)m * (NCHUNK_TOT * 2);

    float2 v = *(const float2*)(p + 2 * lane);
    float a1 = fminf(v.x, v.y), a2 = fmaxf(v.x, v.y);
    #pragma unroll
    for (int off = 32; off > 0; off >>= 1) {
        float o1 = __shfl_xor(a1, off);
        float o2 = __shfl_xor(a2, off);
        float n1 = fminf(a1, o1);
        float n2 = fminf(fmaxf(a1, o1), fminf(a2, o2));
        a1 = n1; a2 = n2;
    }

    const float* px = p + 2 * NCHUNK_TM + lane * 8;
    float4 w0 = *(const float4*)px;
    float4 w1 = *(const float4*)(px + 4);
    float b1 = BIGF, b2 = BIGF;
    merge1(w0.x, b1, b2); merge1(w0.y, b1, b2);
    merge1(w0.z, b1, b2); merge1(w0.w, b1, b2);
    merge1(w1.x, b1, b2); merge1(w1.y, b1, b2);
    merge1(w1.z, b1, b2); merge1(w1.w, b1, b2);
    #pragma unroll
    for (int off = 32; off > 0; off >>= 1) {
        float o1 = __shfl_xor(b1, off);
        float o2 = __shfl_xor(b2, off);
        float n1 = fminf(b1, o1);
        float n2 = fminf(fmaxf(b1, o1), fminf(b2, o2));
        b1 = n1; b2 = n2;
    }

    if (lane == 0) {
        fin[m]           = sqrtf(a1);
        fin[M_Q + m]     = sqrtf(a2);
        fin[2*M_Q + m]   = sqrtf(b1);
        fin[3*M_Q + m]   = sqrtf(b2);
    }
}

// ---------------------------------------------------------------------------
// Pass 4: stats. Both percentile arrays sorted in ONE bitonic pass.
// ---------------------------------------------------------------------------
__global__ __launch_bounds__(1024) void stats_kernel(
    const float* __restrict__ fin, float* __restrict__ out)
{
    __shared__ float s0[1024];
    __shared__ float s1a[1024];
    __shared__ float red[16][6];
    const int t = threadIdx.x;

    float m1 = fin[t];
    float m2 = fin[1024 + t];
    float s1 = fin[2048 + t];
    float s2 = fin[3072 + t];

    const float T = 1.0f / 3.0f;
    float v[6];
    v[0] = (m1 < T * s1 && m1 < T * m2) ? 1.0f : 0.0f;
    v[1] = (s1 < T * m1 && s1 < T * s2) ? 1.0f : 0.0f;
    v[2] = m1; v[3] = s1; v[4] = m2; v[5] = s2;

    #pragma unroll
    for (int off = 32; off > 0; off >>= 1)
        #pragma unroll
        for (int i = 0; i < 6; ++i) v[i] += __shfl_xor(v[i], off);

    int lane = t & 63, wid = t >> 6;
    if (lane == 0) {
        #pragma unroll
        for (int i = 0; i < 6; ++i) red[wid][i] = v[i];
    }
    __syncthreads();
    if (t == 0) {
        float a[6] = {0, 0, 0, 0, 0, 0};
        for (int w = 0; w < 16; ++w)
            for (int i = 0; i < 6; ++i) a[i] += red[w][i];
        out[0] = a[0];
        out[1] = a[1];
        out[2] = a[2] / 1024.0f;
        out[3] = a[3] / 1024.0f;
        out[4] = a[4] / 1024.0f;
        out[5] = a[5] / 1024.0f;
    }

    s0[t]  = m1;
    s1a[t] = s1;
    __syncthreads();

    for (int k = 2; k <= 1024; k <<= 1) {
        for (int jj = k >> 1; jj > 0; jj >>= 1) {
            int ixj = t ^ jj;
            if (ixj > t) {
                bool up = ((t & k) == 0);
                float a = s0[t], b = s0[ixj];
                if ((a > b) == up) { s0[t] = b; s0[ixj] = a; }
                float c = s1a[t], d = s1a[ixj];
                if ((c > d) == up) { s1a[t] = d; s1a[ixj] = c; }
            }
            __syncthreads();
        }
    }

    if (t < 5) {
        const float P[5] = {10.f, 25.f, 50.f, 75.f, 90.f};
        float q = P[t] * 1023.0f / 100.0f;
        int lo = (int)q;
        float fr = q - (float)lo;
        out[6 + t]  = s0[lo]  + fr * (s0[lo + 1]  - s0[lo]);
        out[11 + t] = s1a[lo] + fr * (s1a[lo + 1] - s1a[lo]);
    }
}

// ---------------------------------------------------------------------------
// Fallback path (verified R2 kernels) — used only if ws_size is too small.
// ---------------------------------------------------------------------------
__global__ __launch_bounds__(256) void norms_kernel_fb(
    const float* __restrict__ src, float* __restrict__ dst, int nrows)
{
    int wid = threadIdx.x >> 6;
    int lane = threadIdx.x & 63;
    int row = blockIdx.x * 4 + wid;
    if (row >= nrows) return;
    const float* p = src + (size_t)row * DIM + lane * 8;
    float4 v0 = *(const float4*)p;
    float4 v1 = *(const float4*)(p + 4);
    float s = v0.x*v0.x + v0.y*v0.y + v0.z*v0.z + v0.w*v0.w
            + v1.x*v1.x + v1.y*v1.y + v1.z*v1.z + v1.w*v1.w;
    #pragma unroll
    for (int off = 32; off > 0; off >>= 1) s += __shfl_xor(s, off);
    if (lane == 0) dst[row] = s;
}

__global__ __launch_bounds__(256) void dist_top2_kernel_fb(
    const float* __restrict__ Q, const float* __restrict__ Dset,
    const float* __restrict__ qn, const float* __restrict__ dn,
    float* __restrict__ partial, int chunkGlobalOffset)
{
    __shared__ __align__(16) unsigned short As[64][40];
    __shared__ __align__(16) unsigned short Bs[64][40];

    const int tid  = threadIdx.x;
    const int lane = tid & 63;
    const int wid  = tid >> 6;
    const int mBase = blockIdx.y * 64;
    const int nBase = blockIdx.x * 64;

    const int srow = tid >> 2;
    const int skc  = (tid & 3) * 8;

    const float* qrow = Q    + (size_t)(mBase + srow) * DIM + skc;
    const float* drow = Dset + (size_t)(nBase + srow) * DIM + skc;

    f32x4 acc[4];
    #pragma unroll
    for (int nt = 0; nt < 4; ++nt)
        #pragma unroll
        for (int i = 0; i < 4; ++i) acc[nt][i] = 0.0f;

    const int frow = lane & 15;
    const int fk   = (lane >> 4) * 8;

    for (int ks = 0; ks < DIM; ks += 32) {
        float4 a0 = *(const float4*)(qrow + ks);
        float4 a1 = *(const float4*)(qrow + ks + 4);
        float4 b0 = *(const float4*)(drow + ks);
        float4 b1 = *(const float4*)(drow + ks + 4);

        u16x8 va, vb;
        va[0]=f2bf(a0.x); va[1]=f2bf(a0.y); va[2]=f2bf(a0.z); va[3]=f2bf(a0.w);
        va[4]=f2bf(a1.x); va[5]=f2bf(a1.y); va[6]=f2bf(a1.z); va[7]=f2bf(a1.w);
        vb[0]=f2bf(b0.x); vb[1]=f2bf(b0.y); vb[2]=f2bf(b0.z); vb[3]=f2bf(b0.w);
        vb[4]=f2bf(b1.x); vb[5]=f2bf(b1.y); vb[6]=f2bf(b1.z); vb[7]=f2bf(b1.w);

        *(u16x8*)(&As[srow][skc]) = va;
        *(u16x8*)(&Bs[srow][skc]) = vb;
        __syncthreads();

        bf16x8 af = *(const bf16x8*)(&As[wid * 16 + frow][fk]);
        #pragma unroll
        for (int nt = 0; nt < 4; ++nt) {
            bf16x8 bf = *(const bf16x8*)(&Bs[nt * 16 + frow][fk]);
            acc[nt] = __builtin_amdgcn_mfma_f32_16x16x32_bf16(af, bf, acc[nt], 0, 0, 0);
        }
        __syncthreads();
    }

    const int rbase = mBase + wid * 16 + ((lane >> 4) << 2);
    float q2[4];
    #pragma unroll
    for (int r = 0; r < 4; ++r) q2[r] = qn[rbase + r];

    float d1[4], d2[4];
    #pragma unroll
    for (int r = 0; r < 4; ++r) { d1[r] = BIGF; d2[r] = BIGF; }

    #pragma unroll
    for (int nt = 0; nt < 4; ++nt) {
        float dd = dn[nBase + nt * 16 + (lane & 15)];
        #pragma unroll
        for (int r = 0; r < 4; ++r) {
            float sq = q2[r] + dd - 2.0f * acc[nt][r];
            sq = fmaxf(sq, 0.0f);
            merge1(sq, d1[r], d2[r]);
        }
    }

    #pragma unroll
    for (int r = 0; r < 4; ++r) top2_shfl16(d1[r], d2[r]);

    if ((lane & 15) == 0) {
        int chunkG = chunkGlobalOffset + blockIdx.x;
        #pragma unroll
        for (int r = 0; r < 4; ++r) {
            size_t base = ((size_t)(rbase + r) * NCHUNK_TOT + chunkG) * 2;
            partial[base]     = d1[r];
            partial[base + 1] = d2[r];
        }
    }
}

// ---------------------------------------------------------------------------
extern "C" void kernel_launch(void* const* d_in, const int* in_sizes, int n_in,
                              void* d_out, int out_size, void* d_ws, size_t ws_size,
                              hipStream_t stream) {
    const float* Q  = (const float*)d_in[0];
    const float* TM = (const float*)d_in[1];
    const float* XT = (const float*)d_in[2];
    float* out = (float*)d_out;

    const size_t needMain =
        (size_t)M_Q * DIM * 2 + (size_t)P_ALL * DIM * 2 +
        4 * ((size_t)M_Q + P_ALL + (size_t)M_Q * NCHUNK_TOT * 2 + 4 * M_Q);

    if (ws_size >= needMain) {
        char* w = (char*)d_ws;
        unsigned short* Qb = (unsigned short*)w;
        unsigned short* Db = (unsigned short*)(w + (size_t)M_Q * DIM * 2);
        float* qn = (float*)(w + (size_t)M_Q * DIM * 2 + (size_t)P_ALL * DIM * 2);
        float* dn = qn + M_Q;
        float* partial = dn + P_ALL;
        float* fin = partial + (size_t)M_Q * NCHUNK_TOT * 2;

        convert_norms_kernel<<<dim3(NROWS_ALL / 4), 256, 0, stream>>>(
            Q, TM, XT, Qb, Db, qn, dn);
        dist_mfma_kernel<<<dim3(NCHUNK_TOT * (M_Q / 64)), 256, 0, stream>>>(
            Qb, Db, qn, dn, partial);
        reduce_top2_kernel<<<dim3(M_Q / 4), 256, 0, stream>>>(partial, fin);
        stats_kernel<<<dim3(1), 1024, 0, stream>>>(fin, out);
    } else {
        float* ws = (float*)d_ws;
        float* qn = ws;
        float* dn = ws + M_Q;
        float* partial = dn + P_ALL;
        float* fin = partial + (size_t)M_Q * NCHUNK_TOT * 2;

        norms_kernel_fb<<<dim3(M_Q / 4),  256, 0, stream>>>(Q,  qn, M_Q);
        norms_kernel_fb<<<dim3(P_TM / 4), 256, 0, stream>>>(TM, dn, P_TM);
        norms_kernel_fb<<<dim3(P_XT / 4), 256, 0, stream>>>(XT, dn + P_TM, P_XT);
        dist_top2_kernel_fb<<<dim3(P_TM / 64, M_Q / 64), 256, 0, stream>>>(
            Q, TM, qn, dn, partial, 0);
        dist_top2_kernel_fb<<<dim3(P_XT / 64, M_Q / 64), 256, 0, stream>>>(
            Q, XT, qn, dn + P_TM, partial, NCHUNK_TM);
        reduce_top2_kernel<<<dim3(M_Q / 4), 256, 0, stream>>>(partial, fin);
        stats_kernel<<<dim3(1), 1024, 0, stream>>>(fin, out);
    }
}